// Round 18
// baseline (82.022 us; speedup 1.0000x reference)
//
#include <hip/hip_runtime.h>
#include <math.h>

#define BATCH 2048
#define PDIM  4096
#define PAR   4086
#define CONS  10
#define NW    192     // 64 (cw1 cols) + 128 (ow1 cols)
#define KZT   16      // split-K factor for the big T GEMM

typedef __attribute__((ext_vector_type(8))) short bf16x8;
typedef __attribute__((ext_vector_type(8))) unsigned short ushort8;
typedef __attribute__((ext_vector_type(4))) float f32x4;

// Wpk packed-weight layout (bf16, B-fragment-ready, zero-padded K):
//   ow1cBg  [128][32]  @ 0      B[n][k] = ow1[(4096+k)*128+n], k<10
//   ow1cTBg [16][128]  @ 4096   B[n][k] = ow1[(4096+n)*128+k], n<10
//   ow2Bg   [64][128]  @ 6144   B[n][k] = ow2[k*64+n]
//   ow2TBg  [128][64]  @ 14336  B[n][k] = ow2[n*64+k]
//   cw2Bg   [16][64]   @ 22528  B[n][k] = cw2[k*10+n], n<10
//   cw2TBg  [64][32]   @ 23552  B[n][k] = cw2[n*10+k], k<10
#define WPK_TOTAL 25600

__device__ __forceinline__ unsigned short f2bf(float f) {
    unsigned int u = __float_as_uint(f);
    u += 0x7FFFu + ((u >> 16) & 1u);      // RTNE
    return (unsigned short)(u >> 16);
}
__device__ __forceinline__ float bf2f(unsigned short u) {
    return __uint_as_float(((unsigned int)u) << 16);
}
__device__ __forceinline__ float fast_tanh(float z) {
    float a = fabsf(z);
    float ex = __expf(-2.f * a);                       // e^-2a
    float th = (1.f - ex) * __builtin_amdgcn_rcpf(1.f + ex);
    return copysignf(th, z);
}

// ============ L1: colmean_part + prep_WT + prep_Wcat + weight-pack ============
__global__ __launch_bounds__(256) void prep_all_k(const float* __restrict__ mp,
        const float* __restrict__ cw1, const float* __restrict__ ow1,
        const float* __restrict__ ow2,
        float* __restrict__ epart, unsigned short* __restrict__ WT,
        unsigned short* __restrict__ Wcat, const float* __restrict__ cw2,
        unsigned short* __restrict__ Wpk) {
    __shared__ float tile[64][33];
    const int bid = blockIdx.x, t = threadIdx.x;
    if (bid < 512) {                       // colmean partial: 16 x 32
        int col = (bid & 15) * 256 + t;
        int z = bid >> 4;
        float s = 0.f;
        int r0 = z * 32;
        for (int r = 0; r < 32; ++r) s += mp[(size_t)(r0 + r) * PDIM + col];
        epart[(size_t)z * PDIM + col] = s;
    } else if (bid < 896) {                // prep_WT: 64 k-chunks x 6 j-chunks
        int g = bid - 512;
        int k0 = (g & 63) * 64, j0 = (g >> 6) * 32;
        const float* src; int lds_, jb;
        if (j0 < 64) { src = cw1; lds_ = 64;  jb = j0; }
        else         { src = ow1; lds_ = 128; jb = j0 - 64; }
        int jl = t & 31, kl0 = t >> 5;
        for (int kk = 0; kk < 64; kk += 8)
            tile[kk + kl0][jl] = src[(size_t)(k0 + kk + kl0) * lds_ + jb + jl];
        __syncthreads();
        int kl = t & 63, jl0 = t >> 6;
        for (int jj = 0; jj < 32; jj += 4)
            WT[(size_t)(j0 + jj + jl0) * PDIM + k0 + kl] = f2bf(tile[kl][jj + jl0]);
    } else if (bid < 3968) {               // prep_Wcat: 3072 blocks
        int idx = (bid - 896) * 256 + t;
        int n = idx / NW, j = idx - n * NW;
        float v = (j < 128) ? ow1[(size_t)n * 128 + j] : cw1[(size_t)n * 64 + (j - 128)];
        Wcat[idx] = f2bf(v);
    } else {                               // weight-pack for refine: 100 blocks
        int idx = (bid - 3968) * 256 + t;  // 0..25599
        float v;
        if (idx < 4096)       { int n = idx >> 5, k = idx & 31;
            v = (k < 10) ? ow1[(size_t)(4096 + k) * 128 + n] : 0.f; }
        else if (idx < 6144)  { int i = idx - 4096; int n = i >> 7, k = i & 127;
            v = (n < 10) ? ow1[(size_t)(4096 + n) * 128 + k] : 0.f; }
        else if (idx < 14336) { int i = idx - 6144; int n = i >> 7, k = i & 127;
            v = ow2[k * 64 + n]; }
        else if (idx < 22528) { int i = idx - 14336; int n = i >> 6, k = i & 63;
            v = ow2[n * 64 + k]; }
        else if (idx < 23552) { int i = idx - 22528; int n = i >> 6, k = i & 63;
            v = (n < 10) ? cw2[k * 10 + n] : 0.f; }
        else                  { int i = idx - 23552; int n = i >> 5, k = i & 31;
            v = (k < 10) ? cw2[n * 10 + k] : 0.f; }
        Wpk[idx] = f2bf(v);
    }
}

// ============ L2: colmean_fin + Gram split-K (merged) ============
__global__ __launch_bounds__(256) void fin_gram_k(const float* __restrict__ epart,
        const unsigned short* __restrict__ WT, float* __restrict__ e,
        float* __restrict__ Gpart) {
    __shared__ __align__(16) unsigned short As[64][72];
    __shared__ __align__(16) unsigned short Bs[64][72];
    const int bid = blockIdx.x, t = threadIdx.x;
    if (bid < 16) {                        // colmean finalize
        int col = bid * 256 + t;
        float s = 0.f;
        #pragma unroll
        for (int z = 0; z < 32; ++z) s += epart[(size_t)z * PDIM + col];
        e[col] = s * (1.0f / 1024.0f);
        return;
    }
    int g = bid - 16;                      // 72 blocks: Gram = WT @ WT^T (split-K 8)
    const int kz = g & 7; g >>= 3;
    const int m0 = (g % 3) * 64, n0 = (g / 3) * 64;
    const int w = t >> 6, l = t & 63;
    const int lr = l & 15, lk = (l >> 4) * 8;
    f32x4 acc[4];
    #pragma unroll
    for (int nf = 0; nf < 4; ++nf) acc[nf] = (f32x4){0.f, 0.f, 0.f, 0.f};
    for (int kt = 0; kt < 512; kt += 64) {
        const int kbase = kz * 512 + kt;
        #pragma unroll
        for (int c = 0; c < 2; ++c) {
            int ch = t + c * 256;
            int row = ch >> 3, col8 = (ch & 7) * 8;
            *reinterpret_cast<float4*>(&As[row][col8]) =
                *reinterpret_cast<const float4*>(WT + (size_t)(m0 + row) * PDIM + kbase + col8);
            *reinterpret_cast<float4*>(&Bs[row][col8]) =
                *reinterpret_cast<const float4*>(WT + (size_t)(n0 + row) * PDIM + kbase + col8);
        }
        __syncthreads();
        #pragma unroll
        for (int h = 0; h < 2; ++h) {
            bf16x8 a = *reinterpret_cast<const bf16x8*>(&As[w * 16 + lr][h * 32 + lk]);
            #pragma unroll
            for (int nf = 0; nf < 4; ++nf) {
                bf16x8 b = *reinterpret_cast<const bf16x8*>(&Bs[nf * 16 + lr][h * 32 + lk]);
                acc[nf] = __builtin_amdgcn_mfma_f32_16x16x32_bf16(a, b, acc[nf], 0, 0, 0);
            }
        }
        __syncthreads();
    }
    float* op = Gpart + (size_t)kz * NW * NW + (size_t)(m0 + w * 16 + (l >> 4) * 4) * NW + n0;
    #pragma unroll
    for (int nf = 0; nf < 4; ++nf)
        #pragma unroll
        for (int r = 0; r < 4; ++r)
            op[(size_t)r * NW + nf * 16 + lr] = acc[nf][r];
}

// ============ L3: T = tanh(0.7e+0.3enc) @ Wf — M=64, split-K 16, bf16 partials ============
//             + 144 extra blocks reduce Gpart -> Gram (bf16)
__global__ __launch_bounds__(256) void gemmT_k(const float* __restrict__ tp,
        const float* __restrict__ cons, const float* __restrict__ e,
        const unsigned short* __restrict__ WT, unsigned short* __restrict__ parts,
        const float* __restrict__ Gpart, unsigned short* __restrict__ Gram) {
    __shared__ __align__(16) unsigned short As[64][72];
    __shared__ __align__(16) unsigned short Bs[NW][72];
    const int bid = blockIdx.x, t = threadIdx.x;
    if (bid >= 512) {                      // Gram reduce
        int idx = (bid - 512) * 256 + t;   // 144*256 = 36864
        float s = 0.f;
        #pragma unroll
        for (int z = 0; z < 8; ++z) s += Gpart[(size_t)z * NW * NW + idx];
        Gram[idx] = f2bf(s);
        return;
    }
    const int m0 = (bid >> 4) * 64;        // 32 strips
    const int kz = bid & 15;               // 16 K-chunks of 256
    const int w = t >> 6, l = t & 63;
    const int lr = l & 15, lk = (l >> 4) * 8;

    f32x4 acc[12];
    #pragma unroll
    for (int nf = 0; nf < 12; ++nf) acc[nf] = (f32x4){0.f, 0.f, 0.f, 0.f};

    const int colA = t & 63, rowA0 = t >> 6;
    for (int kt = 0; kt < 256; kt += 64) {
        const int kbase = kz * 256 + kt;
        // A staging: params0 computed on the fly (tanh), never materialized
        const int k = kbase + colA;
        const float ek = e[k];
        #pragma unroll
        for (int c = 0; c < 16; ++c) {
            int row = rowA0 + c * 4;
            int m = m0 + row;
            float encv = (k < PAR) ? tp[(size_t)m * PAR + k] : cons[m * CONS + (k - PAR)];
            As[row][colA] = f2bf(fast_tanh(0.7f * ek + 0.3f * encv));
        }
        #pragma unroll
        for (int c = 0; c < 6; ++c) {      // B staging: 192x64 bf16
            int ch = t + c * 256;
            int row = ch >> 3, col8 = (ch & 7) * 8;
            *reinterpret_cast<float4*>(&Bs[row][col8]) =
                *reinterpret_cast<const float4*>(WT + (size_t)row * PDIM + kbase + col8);
        }
        __syncthreads();
        #pragma unroll
        for (int h = 0; h < 2; ++h) {
            bf16x8 a = *reinterpret_cast<const bf16x8*>(&As[w * 16 + lr][h * 32 + lk]);
            #pragma unroll
            for (int nf = 0; nf < 12; ++nf) {
                bf16x8 b = *reinterpret_cast<const bf16x8*>(&Bs[nf * 16 + lr][h * 32 + lk]);
                acc[nf] = __builtin_amdgcn_mfma_f32_16x16x32_bf16(a, b, acc[nf], 0, 0, 0);
            }
        }
        __syncthreads();
    }
    unsigned short* op = parts + (size_t)kz * BATCH * NW
                       + (size_t)(m0 + w * 16 + (l >> 4) * 4) * NW;
    #pragma unroll
    for (int nf = 0; nf < 12; ++nf)
        #pragma unroll
        for (int r = 0; r < 4; ++r)
            op[(size_t)r * NW + nf * 16 + lr] = f2bf(acc[nf][r]);
}

// ============ L4: fused 3-step refinement — 256 blocks x 8 rows (mirrored to 16) ============
__global__ __launch_bounds__(256) void refine_k(const unsigned short* __restrict__ Tparts,
        const float* __restrict__ cb1, const float* __restrict__ cb2,
        const float* __restrict__ ob1, const float* __restrict__ ob2,
        const float* __restrict__ ow3, const unsigned short* __restrict__ Wpk,
        const unsigned short* __restrict__ Gram, unsigned short* __restrict__ Dsbf) {
    __shared__ __align__(16) float Ts[16][196];
    __shared__ __align__(16) unsigned short hcB[16][72];
    __shared__ __align__(16) unsigned short h1B[16][136];
    __shared__ __align__(16) unsigned short dh2B[16][72];
    __shared__ __align__(16) unsigned short dh1B[16][136];
    __shared__ __align__(16) unsigned short dhcB[16][72];
    __shared__ __align__(16) unsigned short cvA[4][16][40];   // per-wave private
    __shared__ __align__(16) unsigned short dz2A[4][16][40];  // per-wave private

    const int t = threadIdx.x;            // 256 threads, 4 waves
    const int w = t >> 6, l = t & 63;
    const int lr = l & 15, lq = l >> 4, lk = lq * 8;
    const int b8 = blockIdx.x * 8;        // 256 blocks x 8 real rows

    const unsigned short* ow1cBg  = Wpk;
    const unsigned short* ow1cTBg = Wpk + 4096;
    const unsigned short* ow2Bg   = Wpk + 6144;
    const unsigned short* ow2TBg  = Wpk + 14336;
    const unsigned short* cw2Bg   = Wpk + 22528;
    const unsigned short* cw2TBg  = Wpk + 23552;

    // zero-init private cv/dz2 tiles (upper K columns must be 0 for the MFMAs)
    for (int i = t; i < 4 * 640; i += 256) {
        (&cvA[0][0][0])[i] = 0; (&dz2A[0][0][0])[i] = 0;
    }

    // hoisted per-lane biases (L2-hot scalars)
    const float cb1v = cb1[w * 16 + lr];           // stage1: col w*16+lr
    float ob1v[2];
    ob1v[0] = ob1[(w * 2 + 0) * 16 + lr];          // stage3
    ob1v[1] = ob1[(w * 2 + 1) * 16 + lr];
    const float ob2v = ob2[w * 16 + lr];           // stage4
    const float ow3v = ow3[w * 16 + lr];
    const float cb2v = (lr < 10) ? cb2[lr] : 0.f;  // stage2 (all waves)

    // ---- Ts = sum_z Tparts[z][rows][:] (bf16 partials), rows 8..15 mirror 0..7 ----
    for (int i = t; i < 768; i += 256) {
        int rr = i / 48, c4 = (i - rr * 48) * 4;
        const unsigned short* src = Tparts + (size_t)(b8 + (rr & 7)) * NW + c4;
        float s0 = 0.f, s1 = 0.f, s2 = 0.f, s3 = 0.f;
        #pragma unroll
        for (int z = 0; z < KZT; ++z) {
            ushort4 v = *reinterpret_cast<const ushort4*>(src + (size_t)z * BATCH * NW);
            s0 += bf2f(v.x); s1 += bf2f(v.y); s2 += bf2f(v.z); s3 += bf2f(v.w);
        }
        Ts[rr][c4] = s0; Ts[rr][c4 + 1] = s1; Ts[rr][c4 + 2] = s2; Ts[rr][c4 + 3] = s3;
    }
    __syncthreads();

    f32x4 ds1[2], ds2;                    // per-wave dsum slices
    ds1[0] = (f32x4){0.f, 0.f, 0.f, 0.f};
    ds1[1] = (f32x4){0.f, 0.f, 0.f, 0.f};
    ds2    = (f32x4){0.f, 0.f, 0.f, 0.f};
    float sv[4];

    for (int step = 0; step < 3; ++step) {
        unsigned hcm = 0, h1m = 0;        // register relu masks
        // (1) hc = relu(T[:, col w*16+lr] + cb1)
        #pragma unroll
        for (int r = 0; r < 4; ++r) {
            float v = Ts[lq * 4 + r][w * 16 + lr] + cb1v;
            if (v > 0.f) hcm |= 1u << r;
            hcB[lq * 4 + r][w * 16 + lr] = f2bf(fmaxf(v, 0.f));
        }
        __syncthreads();
        // (2) cv = sigmoid(hc @ cw2)   [replicated on all waves -> private cvA]
        {
            f32x4 accv = (f32x4){0.f, 0.f, 0.f, 0.f};
            #pragma unroll
            for (int h = 0; h < 2; ++h) {
                bf16x8 a = *reinterpret_cast<const bf16x8*>(&hcB[lr][h * 32 + lk]);
                bf16x8 b = *reinterpret_cast<const bf16x8*>(cw2Bg + lr * 64 + h * 32 + lk);
                accv = __builtin_amdgcn_mfma_f32_16x16x32_bf16(a, b, accv, 0, 0, 0);
            }
            #pragma unroll
            for (int r = 0; r < 4; ++r) {
                float c = 1.f / (1.f + __expf(-(accv[r] + cb2v)));
                sv[r] = c * (1.f - c);
                cvA[w][lq * 4 + r][lr] = (lr < 10) ? f2bf(c) : (unsigned short)0;
            }
        }
        // (3) h1 = relu(T[:,64:] + ob1 + cv @ ow1c)   [2 nf per wave; no barrier after 2]
        {
            bf16x8 a = *reinterpret_cast<const bf16x8*>(&cvA[w][lr][lk]);
            #pragma unroll
            for (int j = 0; j < 2; ++j) {
                int nf = w * 2 + j;
                bf16x8 b = *reinterpret_cast<const bf16x8*>(ow1cBg + (nf * 16 + lr) * 32 + lk);
                f32x4 acch = __builtin_amdgcn_mfma_f32_16x16x32_bf16(a, b,
                              (f32x4){0.f, 0.f, 0.f, 0.f}, 0, 0, 0);
                #pragma unroll
                for (int r = 0; r < 4; ++r) {
                    int row = lq * 4 + r, col = nf * 16 + lr;
                    float v = acch[r] + Ts[row][64 + col] + ob1v[j];
                    if (v > 0.f) h1m |= 1u << (j * 4 + r);
                    h1B[row][col] = f2bf(fmaxf(v, 0.f));
                }
            }
        }
        __syncthreads();
        // (4) dh2 = (h1@ow2+ob2 > 0) ? ow3 : 0   [1 nf per wave]
        {
            f32x4 accz = (f32x4){0.f, 0.f, 0.f, 0.f};
            #pragma unroll
            for (int kc = 0; kc < 4; ++kc) {
                bf16x8 a = *reinterpret_cast<const bf16x8*>(&h1B[lr][kc * 32 + lk]);
                bf16x8 b = *reinterpret_cast<const bf16x8*>(ow2Bg + (w * 16 + lr) * 128 + kc * 32 + lk);
                accz = __builtin_amdgcn_mfma_f32_16x16x32_bf16(a, b, accz, 0, 0, 0);
            }
            #pragma unroll
            for (int r = 0; r < 4; ++r)
                dh2B[lq * 4 + r][w * 16 + lr] =
                    f2bf((accz[r] + ob2v > 0.f) ? ow3v : 0.f);
        }
        __syncthreads();
        // (5) dh1 = (h1>0) * (dh2 @ ow2^T)   [2 nf per wave, register mask]
        #pragma unroll
        for (int j = 0; j < 2; ++j) {
            int nf = w * 2 + j;
            f32x4 accd = (f32x4){0.f, 0.f, 0.f, 0.f};
            #pragma unroll
            for (int kc = 0; kc < 2; ++kc) {
                bf16x8 a = *reinterpret_cast<const bf16x8*>(&dh2B[lr][kc * 32 + lk]);
                bf16x8 b = *reinterpret_cast<const bf16x8*>(ow2TBg + (nf * 16 + lr) * 64 + kc * 32 + lk);
                accd = __builtin_amdgcn_mfma_f32_16x16x32_bf16(a, b, accd, 0, 0, 0);
            }
            #pragma unroll
            for (int r = 0; r < 4; ++r) {
                float v = (h1m & (1u << (j * 4 + r))) ? accd[r] : 0.f;
                ds1[j][r] += v;
                dh1B[lq * 4 + r][nf * 16 + lr] = f2bf(v);
            }
        }
        __syncthreads();
        // (6) dz2 = (dh1 @ ow1c^T) * cv*(1-cv)   [replicated on all waves -> private dz2A]
        {
            f32x4 accq = (f32x4){0.f, 0.f, 0.f, 0.f};
            #pragma unroll
            for (int kc = 0; kc < 4; ++kc) {
                bf16x8 a = *reinterpret_cast<const bf16x8*>(&dh1B[lr][kc * 32 + lk]);
                bf16x8 b = *reinterpret_cast<const bf16x8*>(ow1cTBg + lr * 128 + kc * 32 + lk);
                accq = __builtin_amdgcn_mfma_f32_16x16x32_bf16(a, b, accq, 0, 0, 0);
            }
            #pragma unroll
            for (int r = 0; r < 4; ++r)
                dz2A[w][lq * 4 + r][lr] = (lr < 10) ? f2bf(accq[r] * sv[r]) : (unsigned short)0;
        }
        // (7) dhc = (hc>0) * (dz2 @ cw2^T)   [1 nf per wave; no barrier after 6]
        {
            bf16x8 a = *reinterpret_cast<const bf16x8*>(&dz2A[w][lr][lk]);
            bf16x8 b = *reinterpret_cast<const bf16x8*>(cw2TBg + (w * 16 + lr) * 32 + lk);
            f32x4 accc = __builtin_amdgcn_mfma_f32_16x16x32_bf16(a, b,
                          (f32x4){0.f, 0.f, 0.f, 0.f}, 0, 0, 0);
            #pragma unroll
            for (int r = 0; r < 4; ++r) {
                float v = (hcm & (1u << r)) ? accc[r] : 0.f;
                ds2[r] += v;
                dhcB[lq * 4 + r][w * 16 + lr] = f2bf(v);
            }
        }
        __syncthreads();
        // (8) T -= 0.01 * [dhc | dh1] @ Gram   [3 nf per wave, Gram from L2]
        if (step < 2) {
            f32x4 accT[3];
            #pragma unroll
            for (int j = 0; j < 3; ++j) accT[j] = (f32x4){0.f, 0.f, 0.f, 0.f};
            #pragma unroll
            for (int kf = 0; kf < 6; ++kf) {
                bf16x8 a = (kf < 2)
                    ? *reinterpret_cast<const bf16x8*>(&dhcB[lr][kf * 32 + lk])
                    : *reinterpret_cast<const bf16x8*>(&dh1B[lr][(kf - 2) * 32 + lk]);
                #pragma unroll
                for (int j = 0; j < 3; ++j) {
                    int nf = w * 3 + j;
                    bf16x8 bg = *reinterpret_cast<const bf16x8*>(
                        Gram + (size_t)(nf * 16 + lr) * NW + kf * 32 + lk);
                    accT[j] = __builtin_amdgcn_mfma_f32_16x16x32_bf16(a, bg, accT[j], 0, 0, 0);
                }
            }
            #pragma unroll
            for (int j = 0; j < 3; ++j)
                #pragma unroll
                for (int r = 0; r < 4; ++r)
                    Ts[lq * 4 + r][(w * 3 + j) * 16 + lr] -= 0.01f * accT[j][r];
            __syncthreads();
        }
    }
    // Dsbf = [sum dh1 | sum dhc] bf16 — only real rows (lq<2 -> rows 0..7)
    if (lq < 2) {
        #pragma unroll
        for (int j = 0; j < 2; ++j)
            #pragma unroll
            for (int r = 0; r < 4; ++r)
                Dsbf[(size_t)(b8 + lq * 4 + r) * NW + (w * 2 + j) * 16 + lr] = f2bf(ds1[j][r]);
        #pragma unroll
        for (int r = 0; r < 4; ++r)
            Dsbf[(size_t)(b8 + lq * 4 + r) * NW + 128 + w * 16 + lr] = f2bf(ds2[r]);
    }
}

// ============ L5: pm = tanh(0.7e+0.3enc) - 0.01 * Dsum @ Wcat^T ============
// v5: barrier-free GEMM phase — A from Dsbf and B from Wcat both direct L2
// fragment loads (refine's proven pattern); only 1 __syncthreads (corr).
__global__ __launch_bounds__(256) void final_k(const unsigned short* __restrict__ Dsbf,
        const unsigned short* __restrict__ Wcat, const float* __restrict__ tp,
        const float* __restrict__ cons, const float* __restrict__ e,
        float* __restrict__ pm) {
    __shared__ __align__(16) unsigned short corr[64][132];         // 16896 B
    const int bid = blockIdx.x, t = threadIdx.x;
    const int m0 = (bid >> 5) * 64;
    const int n0 = (bid & 31) * 128;
    const int w = t >> 6, l = t & 63;
    const int lr = l & 15, lq = l >> 4, lk = lq * 8;

    f32x4 acc[8];
    #pragma unroll
    for (int nf = 0; nf < 8; ++nf) acc[nf] = (f32x4){0.f, 0.f, 0.f, 0.f};

    const unsigned short* ap = Dsbf + (size_t)(m0 + w * 16 + lr) * NW;
    #pragma unroll
    for (int ks = 0; ks < 6; ++ks) {       // K=192 in 6 steps of 32; zero barriers
        bf16x8 a = *reinterpret_cast<const bf16x8*>(ap + ks * 32 + lk);
        #pragma unroll
        for (int nf = 0; nf < 8; ++nf) {
            bf16x8 b = *reinterpret_cast<const bf16x8*>(
                Wcat + (size_t)(n0 + nf * 16 + lr) * NW + ks * 32 + lk);
            acc[nf] = __builtin_amdgcn_mfma_f32_16x16x32_bf16(a, b, acc[nf], 0, 0, 0);
        }
    }
    // ---- stage corrections 0.01*acc into LDS (bf16) in fragment order ----
    const int lrow = w * 16 + lq * 4;
    #pragma unroll
    for (int nf = 0; nf < 8; ++nf)
        #pragma unroll
        for (int r = 0; r < 4; ++r)
            corr[lrow + r][nf * 16 + lr] = f2bf(0.01f * acc[nf][r]);
    __syncthreads();
    // ---- coalesced stream: lane owns 4 cols, 8 rows per thread (float4 store) ----
    const int c4 = (t & 31) * 4;           // local col 0..124
    const int rb = t >> 5;                 // row offset 0..7
    const int n = n0 + c4;
    if (n + 3 < PAR) {                     // fast path (all tiles except last n0)
        const float4 ev = *reinterpret_cast<const float4*>(e + n);
        const float a0 = 0.7f * ev.x, a1 = 0.7f * ev.y;
        const float a2 = 0.7f * ev.z, a3 = 0.7f * ev.w;
        #pragma unroll 4
        for (int it = 0; it < 8; ++it) {
            int row = it * 8 + rb;
            int m = m0 + row;
            const float* tpp = tp + (size_t)m * PAR + n;
            float2 tv0 = *reinterpret_cast<const float2*>(tpp);      // 8B-aligned always
            float2 tv1 = *reinterpret_cast<const float2*>(tpp + 2);
            uint2 cw = *reinterpret_cast<const uint2*>(&corr[row][c4]);
            float4 o;
            o.x = fast_tanh(a0 + 0.3f * tv0.x) - bf2f((unsigned short)(cw.x & 0xFFFF));
            o.y = fast_tanh(a1 + 0.3f * tv0.y) - bf2f((unsigned short)(cw.x >> 16));
            o.z = fast_tanh(a2 + 0.3f * tv1.x) - bf2f((unsigned short)(cw.y & 0xFFFF));
            o.w = fast_tanh(a3 + 0.3f * tv1.y) - bf2f((unsigned short)(cw.y >> 16));
            *reinterpret_cast<float4*>(pm + (size_t)m * PDIM + n) = o;
        }
    } else {                               // boundary lanes: per-element
        for (int it = 0; it < 8; ++it) {
            int row = it * 8 + rb;
            int m = m0 + row;
            #pragma unroll
            for (int jj = 0; jj < 4; ++jj) {
                int nn = n + jj;
                float v = (nn < PAR) ? tp[(size_t)m * PAR + nn] : cons[m * CONS + (nn - PAR)];
                pm[(size_t)m * PDIM + nn] = fast_tanh(0.7f * e[nn] + 0.3f * v)
                                          - bf2f(corr[row][c4 + jj]);
            }
        }
    }
}

extern "C" void kernel_launch(void* const* d_in, const int* in_sizes, int n_in,
                              void* d_out, int out_size, void* d_ws, size_t ws_size,
                              hipStream_t stream) {
    const float* tp   = (const float*)d_in[0];
    const float* cons = (const float*)d_in[1];
    // d_in[2] transverse_field, d_in[3] coupling: DEAD CODE (annealing is identity)
    const float* mp   = (const float*)d_in[4];
    const float* cw1  = (const float*)d_in[5];
    const float* cb1  = (const float*)d_in[6];
    const float* cw2  = (const float*)d_in[7];
    const float* cb2  = (const float*)d_in[8];
    const float* ow1  = (const float*)d_in[9];
    const float* ob1  = (const float*)d_in[10];
    const float* ow2  = (const float*)d_in[11];
    const float* ob2  = (const float*)d_in[12];
    const float* ow3  = (const float*)d_in[13];
    float* pm = (float*)d_out;

    float* f = (float*)d_ws;
    float* e      = f;  f += 4096;
    float* epart  = f;  f += 32 * 4096;
    float* Gpart  = f;  f += 8 * NW * NW;
    unsigned short* u = (unsigned short*)f;
    unsigned short* Tparts = u;  u += (size_t)KZT * BATCH * NW;   // bf16 partials
    unsigned short* WT   = u;  u += NW * PDIM;
    unsigned short* Wcat = u;  u += PDIM * NW;
    unsigned short* Gram = u;  u += NW * NW;
    unsigned short* Dsbf = u;  u += BATCH * NW;
    unsigned short* Wpk  = u;

    prep_all_k<<<4068, 256, 0, stream>>>(mp, cw1, ow1, ow2, epart, WT, Wcat, cw2, Wpk);
    fin_gram_k<<<88, 256, 0, stream>>>(epart, WT, e, Gpart);
    gemmT_k<<<656, 256, 0, stream>>>(tp, cons, e, WT, Tparts, Gpart, Gram);
    refine_k<<<256, 256, 0, stream>>>(Tparts, cb1, cb2, ob1, ob2, ow3, Wpk, Gram, Dsbf);
    final_k<<<1024, 256, 0, stream>>>(Dsbf, Wcat, tp, cons, e, pm);
}

// Round 19
// 68.192 us; speedup vs baseline: 1.2028x; 1.2028x over previous
//
#include <hip/hip_runtime.h>
#include <math.h>

#define BATCH 2048
#define PDIM  4096
#define PAR   4086
#define CONS  10
#define NW    192     // 64 (cw1 cols) + 128 (ow1 cols)
#define KZT   16      // split-K factor for the big T GEMM

typedef __attribute__((ext_vector_type(8))) short bf16x8;
typedef __attribute__((ext_vector_type(8))) unsigned short ushort8;
typedef __attribute__((ext_vector_type(4))) float f32x4;

// Wpk packed-weight layout (bf16, B-fragment-ready, zero-padded K):
//   ow1cBg  [128][32]  @ 0      B[n][k] = ow1[(4096+k)*128+n], k<10
//   ow1cTBg [16][128]  @ 4096   B[n][k] = ow1[(4096+n)*128+k], n<10
//   ow2Bg   [64][128]  @ 6144   B[n][k] = ow2[k*64+n]
//   ow2TBg  [128][64]  @ 14336  B[n][k] = ow2[n*64+k]
//   cw2Bg   [16][64]   @ 22528  B[n][k] = cw2[k*10+n], n<10
//   cw2TBg  [64][32]   @ 23552  B[n][k] = cw2[n*10+k], k<10
#define WPK_TOTAL 25600

__device__ __forceinline__ unsigned short f2bf(float f) {
    unsigned int u = __float_as_uint(f);
    u += 0x7FFFu + ((u >> 16) & 1u);      // RTNE
    return (unsigned short)(u >> 16);
}
__device__ __forceinline__ float bf2f(unsigned short u) {
    return __uint_as_float(((unsigned int)u) << 16);
}
__device__ __forceinline__ float fast_tanh(float z) {
    float a = fabsf(z);
    float ex = __expf(-2.f * a);                       // e^-2a
    float th = (1.f - ex) * __builtin_amdgcn_rcpf(1.f + ex);
    return copysignf(th, z);
}

// ============ L1: colmean_part + prep_WT + prep_Wcat + weight-pack ============
__global__ __launch_bounds__(256) void prep_all_k(const float* __restrict__ mp,
        const float* __restrict__ cw1, const float* __restrict__ ow1,
        const float* __restrict__ ow2,
        float* __restrict__ epart, unsigned short* __restrict__ WT,
        unsigned short* __restrict__ Wcat, const float* __restrict__ cw2,
        unsigned short* __restrict__ Wpk) {
    __shared__ float tile[64][33];
    const int bid = blockIdx.x, t = threadIdx.x;
    if (bid < 512) {                       // colmean partial: 16 x 32
        int col = (bid & 15) * 256 + t;
        int z = bid >> 4;
        float s = 0.f;
        int r0 = z * 32;
        for (int r = 0; r < 32; ++r) s += mp[(size_t)(r0 + r) * PDIM + col];
        epart[(size_t)z * PDIM + col] = s;
    } else if (bid < 896) {                // prep_WT: 64 k-chunks x 6 j-chunks
        int g = bid - 512;
        int k0 = (g & 63) * 64, j0 = (g >> 6) * 32;
        const float* src; int lds_, jb;
        if (j0 < 64) { src = cw1; lds_ = 64;  jb = j0; }
        else         { src = ow1; lds_ = 128; jb = j0 - 64; }
        int jl = t & 31, kl0 = t >> 5;
        for (int kk = 0; kk < 64; kk += 8)
            tile[kk + kl0][jl] = src[(size_t)(k0 + kk + kl0) * lds_ + jb + jl];
        __syncthreads();
        int kl = t & 63, jl0 = t >> 6;
        for (int jj = 0; jj < 32; jj += 4)
            WT[(size_t)(j0 + jj + jl0) * PDIM + k0 + kl] = f2bf(tile[kl][jj + jl0]);
    } else if (bid < 3968) {               // prep_Wcat: 3072 blocks
        int idx = (bid - 896) * 256 + t;
        int n = idx / NW, j = idx - n * NW;
        float v = (j < 128) ? ow1[(size_t)n * 128 + j] : cw1[(size_t)n * 64 + (j - 128)];
        Wcat[idx] = f2bf(v);
    } else {                               // weight-pack for refine: 100 blocks
        int idx = (bid - 3968) * 256 + t;  // 0..25599
        float v;
        if (idx < 4096)       { int n = idx >> 5, k = idx & 31;
            v = (k < 10) ? ow1[(size_t)(4096 + k) * 128 + n] : 0.f; }
        else if (idx < 6144)  { int i = idx - 4096; int n = i >> 7, k = i & 127;
            v = (n < 10) ? ow1[(size_t)(4096 + n) * 128 + k] : 0.f; }
        else if (idx < 14336) { int i = idx - 6144; int n = i >> 7, k = i & 127;
            v = ow2[k * 64 + n]; }
        else if (idx < 22528) { int i = idx - 14336; int n = i >> 6, k = i & 63;
            v = ow2[n * 64 + k]; }
        else if (idx < 23552) { int i = idx - 22528; int n = i >> 6, k = i & 63;
            v = (n < 10) ? cw2[k * 10 + n] : 0.f; }
        else                  { int i = idx - 23552; int n = i >> 5, k = i & 31;
            v = (k < 10) ? cw2[n * 10 + k] : 0.f; }
        Wpk[idx] = f2bf(v);
    }
}

// ============ L2: colmean_fin + Gram split-K (merged) ============
__global__ __launch_bounds__(256) void fin_gram_k(const float* __restrict__ epart,
        const unsigned short* __restrict__ WT, float* __restrict__ e,
        float* __restrict__ Gpart) {
    __shared__ __align__(16) unsigned short As[64][72];
    __shared__ __align__(16) unsigned short Bs[64][72];
    const int bid = blockIdx.x, t = threadIdx.x;
    if (bid < 16) {                        // colmean finalize
        int col = bid * 256 + t;
        float s = 0.f;
        #pragma unroll
        for (int z = 0; z < 32; ++z) s += epart[(size_t)z * PDIM + col];
        e[col] = s * (1.0f / 1024.0f);
        return;
    }
    int g = bid - 16;                      // 72 blocks: Gram = WT @ WT^T (split-K 8)
    const int kz = g & 7; g >>= 3;
    const int m0 = (g % 3) * 64, n0 = (g / 3) * 64;
    const int w = t >> 6, l = t & 63;
    const int lr = l & 15, lk = (l >> 4) * 8;
    f32x4 acc[4];
    #pragma unroll
    for (int nf = 0; nf < 4; ++nf) acc[nf] = (f32x4){0.f, 0.f, 0.f, 0.f};
    for (int kt = 0; kt < 512; kt += 64) {
        const int kbase = kz * 512 + kt;
        #pragma unroll
        for (int c = 0; c < 2; ++c) {
            int ch = t + c * 256;
            int row = ch >> 3, col8 = (ch & 7) * 8;
            *reinterpret_cast<float4*>(&As[row][col8]) =
                *reinterpret_cast<const float4*>(WT + (size_t)(m0 + row) * PDIM + kbase + col8);
            *reinterpret_cast<float4*>(&Bs[row][col8]) =
                *reinterpret_cast<const float4*>(WT + (size_t)(n0 + row) * PDIM + kbase + col8);
        }
        __syncthreads();
        #pragma unroll
        for (int h = 0; h < 2; ++h) {
            bf16x8 a = *reinterpret_cast<const bf16x8*>(&As[w * 16 + lr][h * 32 + lk]);
            #pragma unroll
            for (int nf = 0; nf < 4; ++nf) {
                bf16x8 b = *reinterpret_cast<const bf16x8*>(&Bs[nf * 16 + lr][h * 32 + lk]);
                acc[nf] = __builtin_amdgcn_mfma_f32_16x16x32_bf16(a, b, acc[nf], 0, 0, 0);
            }
        }
        __syncthreads();
    }
    float* op = Gpart + (size_t)kz * NW * NW + (size_t)(m0 + w * 16 + (l >> 4) * 4) * NW + n0;
    #pragma unroll
    for (int nf = 0; nf < 4; ++nf)
        #pragma unroll
        for (int r = 0; r < 4; ++r)
            op[(size_t)r * NW + nf * 16 + lr] = acc[nf][r];
}

// ============ L3: T = tanh(0.7e+0.3enc) @ Wf — M=64, split-K 16, bf16 partials ============
//             + 144 extra blocks reduce Gpart -> Gram (bf16)
__global__ __launch_bounds__(256) void gemmT_k(const float* __restrict__ tp,
        const float* __restrict__ cons, const float* __restrict__ e,
        const unsigned short* __restrict__ WT, unsigned short* __restrict__ parts,
        const float* __restrict__ Gpart, unsigned short* __restrict__ Gram) {
    __shared__ __align__(16) unsigned short As[64][72];
    __shared__ __align__(16) unsigned short Bs[NW][72];
    const int bid = blockIdx.x, t = threadIdx.x;
    if (bid >= 512) {                      // Gram reduce
        int idx = (bid - 512) * 256 + t;   // 144*256 = 36864
        float s = 0.f;
        #pragma unroll
        for (int z = 0; z < 8; ++z) s += Gpart[(size_t)z * NW * NW + idx];
        Gram[idx] = f2bf(s);
        return;
    }
    const int m0 = (bid >> 4) * 64;        // 32 strips
    const int kz = bid & 15;               // 16 K-chunks of 256
    const int w = t >> 6, l = t & 63;
    const int lr = l & 15, lk = (l >> 4) * 8;

    f32x4 acc[12];
    #pragma unroll
    for (int nf = 0; nf < 12; ++nf) acc[nf] = (f32x4){0.f, 0.f, 0.f, 0.f};

    const int colA = t & 63, rowA0 = t >> 6;
    for (int kt = 0; kt < 256; kt += 64) {
        const int kbase = kz * 256 + kt;
        // A staging: params0 computed on the fly (tanh), never materialized
        const int k = kbase + colA;
        const float ek = e[k];
        #pragma unroll
        for (int c = 0; c < 16; ++c) {
            int row = rowA0 + c * 4;
            int m = m0 + row;
            float encv = (k < PAR) ? tp[(size_t)m * PAR + k] : cons[m * CONS + (k - PAR)];
            As[row][colA] = f2bf(fast_tanh(0.7f * ek + 0.3f * encv));
        }
        #pragma unroll
        for (int c = 0; c < 6; ++c) {      // B staging: 192x64 bf16
            int ch = t + c * 256;
            int row = ch >> 3, col8 = (ch & 7) * 8;
            *reinterpret_cast<float4*>(&Bs[row][col8]) =
                *reinterpret_cast<const float4*>(WT + (size_t)row * PDIM + kbase + col8);
        }
        __syncthreads();
        #pragma unroll
        for (int h = 0; h < 2; ++h) {
            bf16x8 a = *reinterpret_cast<const bf16x8*>(&As[w * 16 + lr][h * 32 + lk]);
            #pragma unroll
            for (int nf = 0; nf < 12; ++nf) {
                bf16x8 b = *reinterpret_cast<const bf16x8*>(&Bs[nf * 16 + lr][h * 32 + lk]);
                acc[nf] = __builtin_amdgcn_mfma_f32_16x16x32_bf16(a, b, acc[nf], 0, 0, 0);
            }
        }
        __syncthreads();
    }
    unsigned short* op = parts + (size_t)kz * BATCH * NW
                       + (size_t)(m0 + w * 16 + (l >> 4) * 4) * NW;
    #pragma unroll
    for (int nf = 0; nf < 12; ++nf)
        #pragma unroll
        for (int r = 0; r < 4; ++r)
            op[(size_t)r * NW + nf * 16 + lr] = f2bf(acc[nf][r]);
}

// ============ L4: fused 3-step refinement — 256 blocks x 8 rows (mirrored to 16) ============
__global__ __launch_bounds__(256) void refine_k(const unsigned short* __restrict__ Tparts,
        const float* __restrict__ cb1, const float* __restrict__ cb2,
        const float* __restrict__ ob1, const float* __restrict__ ob2,
        const float* __restrict__ ow3, const unsigned short* __restrict__ Wpk,
        const unsigned short* __restrict__ Gram, unsigned short* __restrict__ Dsbf) {
    __shared__ __align__(16) float Ts[16][196];
    __shared__ __align__(16) unsigned short hcB[16][72];
    __shared__ __align__(16) unsigned short h1B[16][136];
    __shared__ __align__(16) unsigned short dh2B[16][72];
    __shared__ __align__(16) unsigned short dh1B[16][136];
    __shared__ __align__(16) unsigned short dhcB[16][72];
    __shared__ __align__(16) unsigned short cvA[4][16][40];   // per-wave private
    __shared__ __align__(16) unsigned short dz2A[4][16][40];  // per-wave private

    const int t = threadIdx.x;            // 256 threads, 4 waves
    const int w = t >> 6, l = t & 63;
    const int lr = l & 15, lq = l >> 4, lk = lq * 8;
    const int b8 = blockIdx.x * 8;        // 256 blocks x 8 real rows

    const unsigned short* ow1cBg  = Wpk;
    const unsigned short* ow1cTBg = Wpk + 4096;
    const unsigned short* ow2Bg   = Wpk + 6144;
    const unsigned short* ow2TBg  = Wpk + 14336;
    const unsigned short* cw2Bg   = Wpk + 22528;
    const unsigned short* cw2TBg  = Wpk + 23552;

    // zero-init private cv/dz2 tiles (upper K columns must be 0 for the MFMAs)
    for (int i = t; i < 4 * 640; i += 256) {
        (&cvA[0][0][0])[i] = 0; (&dz2A[0][0][0])[i] = 0;
    }

    // hoisted per-lane biases (L2-hot scalars)
    const float cb1v = cb1[w * 16 + lr];           // stage1: col w*16+lr
    float ob1v[2];
    ob1v[0] = ob1[(w * 2 + 0) * 16 + lr];          // stage3
    ob1v[1] = ob1[(w * 2 + 1) * 16 + lr];
    const float ob2v = ob2[w * 16 + lr];           // stage4
    const float ow3v = ow3[w * 16 + lr];
    const float cb2v = (lr < 10) ? cb2[lr] : 0.f;  // stage2 (all waves)

    // ---- Ts = sum_z Tparts[z][rows][:] (bf16 partials), rows 8..15 mirror 0..7 ----
    for (int i = t; i < 768; i += 256) {
        int rr = i / 48, c4 = (i - rr * 48) * 4;
        const unsigned short* src = Tparts + (size_t)(b8 + (rr & 7)) * NW + c4;
        float s0 = 0.f, s1 = 0.f, s2 = 0.f, s3 = 0.f;
        #pragma unroll
        for (int z = 0; z < KZT; ++z) {
            ushort4 v = *reinterpret_cast<const ushort4*>(src + (size_t)z * BATCH * NW);
            s0 += bf2f(v.x); s1 += bf2f(v.y); s2 += bf2f(v.z); s3 += bf2f(v.w);
        }
        Ts[rr][c4] = s0; Ts[rr][c4 + 1] = s1; Ts[rr][c4 + 2] = s2; Ts[rr][c4 + 3] = s3;
    }
    __syncthreads();

    f32x4 ds1[2], ds2;                    // per-wave dsum slices
    ds1[0] = (f32x4){0.f, 0.f, 0.f, 0.f};
    ds1[1] = (f32x4){0.f, 0.f, 0.f, 0.f};
    ds2    = (f32x4){0.f, 0.f, 0.f, 0.f};
    float sv[4];

    for (int step = 0; step < 3; ++step) {
        unsigned hcm = 0, h1m = 0;        // register relu masks
        // (1) hc = relu(T[:, col w*16+lr] + cb1)
        #pragma unroll
        for (int r = 0; r < 4; ++r) {
            float v = Ts[lq * 4 + r][w * 16 + lr] + cb1v;
            if (v > 0.f) hcm |= 1u << r;
            hcB[lq * 4 + r][w * 16 + lr] = f2bf(fmaxf(v, 0.f));
        }
        __syncthreads();
        // (2) cv = sigmoid(hc @ cw2)   [replicated on all waves -> private cvA]
        {
            f32x4 accv = (f32x4){0.f, 0.f, 0.f, 0.f};
            #pragma unroll
            for (int h = 0; h < 2; ++h) {
                bf16x8 a = *reinterpret_cast<const bf16x8*>(&hcB[lr][h * 32 + lk]);
                bf16x8 b = *reinterpret_cast<const bf16x8*>(cw2Bg + lr * 64 + h * 32 + lk);
                accv = __builtin_amdgcn_mfma_f32_16x16x32_bf16(a, b, accv, 0, 0, 0);
            }
            #pragma unroll
            for (int r = 0; r < 4; ++r) {
                float c = 1.f / (1.f + __expf(-(accv[r] + cb2v)));
                sv[r] = c * (1.f - c);
                cvA[w][lq * 4 + r][lr] = (lr < 10) ? f2bf(c) : (unsigned short)0;
            }
        }
        // (3) h1 = relu(T[:,64:] + ob1 + cv @ ow1c)   [2 nf per wave; no barrier after 2]
        {
            bf16x8 a = *reinterpret_cast<const bf16x8*>(&cvA[w][lr][lk]);
            #pragma unroll
            for (int j = 0; j < 2; ++j) {
                int nf = w * 2 + j;
                bf16x8 b = *reinterpret_cast<const bf16x8*>(ow1cBg + (nf * 16 + lr) * 32 + lk);
                f32x4 acch = __builtin_amdgcn_mfma_f32_16x16x32_bf16(a, b,
                              (f32x4){0.f, 0.f, 0.f, 0.f}, 0, 0, 0);
                #pragma unroll
                for (int r = 0; r < 4; ++r) {
                    int row = lq * 4 + r, col = nf * 16 + lr;
                    float v = acch[r] + Ts[row][64 + col] + ob1v[j];
                    if (v > 0.f) h1m |= 1u << (j * 4 + r);
                    h1B[row][col] = f2bf(fmaxf(v, 0.f));
                }
            }
        }
        __syncthreads();
        // (4) dh2 = (h1@ow2+ob2 > 0) ? ow3 : 0   [1 nf per wave]
        {
            f32x4 accz = (f32x4){0.f, 0.f, 0.f, 0.f};
            #pragma unroll
            for (int kc = 0; kc < 4; ++kc) {
                bf16x8 a = *reinterpret_cast<const bf16x8*>(&h1B[lr][kc * 32 + lk]);
                bf16x8 b = *reinterpret_cast<const bf16x8*>(ow2Bg + (w * 16 + lr) * 128 + kc * 32 + lk);
                accz = __builtin_amdgcn_mfma_f32_16x16x32_bf16(a, b, accz, 0, 0, 0);
            }
            #pragma unroll
            for (int r = 0; r < 4; ++r)
                dh2B[lq * 4 + r][w * 16 + lr] =
                    f2bf((accz[r] + ob2v > 0.f) ? ow3v : 0.f);
        }
        __syncthreads();
        // (5) dh1 = (h1>0) * (dh2 @ ow2^T)   [2 nf per wave, register mask]
        #pragma unroll
        for (int j = 0; j < 2; ++j) {
            int nf = w * 2 + j;
            f32x4 accd = (f32x4){0.f, 0.f, 0.f, 0.f};
            #pragma unroll
            for (int kc = 0; kc < 2; ++kc) {
                bf16x8 a = *reinterpret_cast<const bf16x8*>(&dh2B[lr][kc * 32 + lk]);
                bf16x8 b = *reinterpret_cast<const bf16x8*>(ow2TBg + (nf * 16 + lr) * 64 + kc * 32 + lk);
                accd = __builtin_amdgcn_mfma_f32_16x16x32_bf16(a, b, accd, 0, 0, 0);
            }
            #pragma unroll
            for (int r = 0; r < 4; ++r) {
                float v = (h1m & (1u << (j * 4 + r))) ? accd[r] : 0.f;
                ds1[j][r] += v;
                dh1B[lq * 4 + r][nf * 16 + lr] = f2bf(v);
            }
        }
        __syncthreads();
        // (6) dz2 = (dh1 @ ow1c^T) * cv*(1-cv)   [replicated on all waves -> private dz2A]
        {
            f32x4 accq = (f32x4){0.f, 0.f, 0.f, 0.f};
            #pragma unroll
            for (int kc = 0; kc < 4; ++kc) {
                bf16x8 a = *reinterpret_cast<const bf16x8*>(&dh1B[lr][kc * 32 + lk]);
                bf16x8 b = *reinterpret_cast<const bf16x8*>(ow1cTBg + lr * 128 + kc * 32 + lk);
                accq = __builtin_amdgcn_mfma_f32_16x16x32_bf16(a, b, accq, 0, 0, 0);
            }
            #pragma unroll
            for (int r = 0; r < 4; ++r)
                dz2A[w][lq * 4 + r][lr] = (lr < 10) ? f2bf(accq[r] * sv[r]) : (unsigned short)0;
        }
        // (7) dhc = (hc>0) * (dz2 @ cw2^T)   [1 nf per wave; no barrier after 6]
        {
            bf16x8 a = *reinterpret_cast<const bf16x8*>(&dz2A[w][lr][lk]);
            bf16x8 b = *reinterpret_cast<const bf16x8*>(cw2TBg + (w * 16 + lr) * 32 + lk);
            f32x4 accc = __builtin_amdgcn_mfma_f32_16x16x32_bf16(a, b,
                          (f32x4){0.f, 0.f, 0.f, 0.f}, 0, 0, 0);
            #pragma unroll
            for (int r = 0; r < 4; ++r) {
                float v = (hcm & (1u << r)) ? accc[r] : 0.f;
                ds2[r] += v;
                dhcB[lq * 4 + r][w * 16 + lr] = f2bf(v);
            }
        }
        __syncthreads();
        // (8) T -= 0.01 * [dhc | dh1] @ Gram   [3 nf per wave, Gram from L2]
        if (step < 2) {
            f32x4 accT[3];
            #pragma unroll
            for (int j = 0; j < 3; ++j) accT[j] = (f32x4){0.f, 0.f, 0.f, 0.f};
            #pragma unroll
            for (int kf = 0; kf < 6; ++kf) {
                bf16x8 a = (kf < 2)
                    ? *reinterpret_cast<const bf16x8*>(&dhcB[lr][kf * 32 + lk])
                    : *reinterpret_cast<const bf16x8*>(&dh1B[lr][(kf - 2) * 32 + lk]);
                #pragma unroll
                for (int j = 0; j < 3; ++j) {
                    int nf = w * 3 + j;
                    bf16x8 bg = *reinterpret_cast<const bf16x8*>(
                        Gram + (size_t)(nf * 16 + lr) * NW + kf * 32 + lk);
                    accT[j] = __builtin_amdgcn_mfma_f32_16x16x32_bf16(a, bg, accT[j], 0, 0, 0);
                }
            }
            #pragma unroll
            for (int j = 0; j < 3; ++j)
                #pragma unroll
                for (int r = 0; r < 4; ++r)
                    Ts[lq * 4 + r][(w * 3 + j) * 16 + lr] -= 0.01f * accT[j][r];
            __syncthreads();
        }
    }
    // Dsbf = [sum dh1 | sum dhc] bf16 — only real rows (lq<2 -> rows 0..7)
    if (lq < 2) {
        #pragma unroll
        for (int j = 0; j < 2; ++j)
            #pragma unroll
            for (int r = 0; r < 4; ++r)
                Dsbf[(size_t)(b8 + lq * 4 + r) * NW + (w * 2 + j) * 16 + lr] = f2bf(ds1[j][r]);
        #pragma unroll
        for (int r = 0; r < 4; ++r)
            Dsbf[(size_t)(b8 + lq * 4 + r) * NW + 128 + w * 16 + lr] = f2bf(ds2[r]);
    }
}

// ============ L5: pm = tanh(0.7e+0.3enc) - 0.01 * Dsum @ Wcat^T ============
// v3 (best measured): N-tile 128 (1024 blocks = 4/CU); A-fragments direct from L2;
// B via LDS; corr overlay; 8-rows-per-thread float4 stream.
__global__ __launch_bounds__(256) void final_k(const unsigned short* __restrict__ Dsbf,
        const unsigned short* __restrict__ Wcat, const float* __restrict__ tp,
        const float* __restrict__ cons, const float* __restrict__ e,
        float* __restrict__ pm) {
    __shared__ __align__(16) unsigned short Bs[128][72];           // 18432 B
    unsigned short (*corr)[132] = reinterpret_cast<unsigned short(*)[132]>(&Bs[0][0]); // 16896 B overlay
    const int bid = blockIdx.x, t = threadIdx.x;
    const int m0 = (bid >> 5) * 64;
    const int n0 = (bid & 31) * 128;
    const int w = t >> 6, l = t & 63;
    const int lr = l & 15, lq = l >> 4, lk = lq * 8;

    f32x4 acc[8];
    #pragma unroll
    for (int nf = 0; nf < 8; ++nf) acc[nf] = (f32x4){0.f, 0.f, 0.f, 0.f};

    const int arow = m0 + w * 16 + lr;     // A-fragment row (direct from L2)
    for (int kt = 0; kt < NW; kt += 64) {
        #pragma unroll
        for (int c = 0; c < 4; ++c) {      // B: Wcat 128x64 -> LDS
            int ch = t + c * 256;
            int row = ch >> 3, col8 = (ch & 7) * 8;
            *reinterpret_cast<float4*>(&Bs[row][col8]) =
                *reinterpret_cast<const float4*>(Wcat + (size_t)(n0 + row) * NW + kt + col8);
        }
        __syncthreads();
        #pragma unroll
        for (int h = 0; h < 2; ++h) {
            bf16x8 a = *reinterpret_cast<const bf16x8*>(
                Dsbf + (size_t)arow * NW + kt + h * 32 + lk);
            #pragma unroll
            for (int nf = 0; nf < 8; ++nf) {
                bf16x8 b = *reinterpret_cast<const bf16x8*>(&Bs[nf * 16 + lr][h * 32 + lk]);
                acc[nf] = __builtin_amdgcn_mfma_f32_16x16x32_bf16(a, b, acc[nf], 0, 0, 0);
            }
        }
        __syncthreads();                   // last one also guards the Bs->corr overlay
    }
    // ---- stage corrections 0.01*acc into LDS (bf16) in fragment order ----
    const int lrow = w * 16 + lq * 4;
    #pragma unroll
    for (int nf = 0; nf < 8; ++nf)
        #pragma unroll
        for (int r = 0; r < 4; ++r)
            corr[lrow + r][nf * 16 + lr] = f2bf(0.01f * acc[nf][r]);
    __syncthreads();
    // ---- coalesced stream: lane owns 4 cols, 8 rows per thread (float4 store) ----
    const int c4 = (t & 31) * 4;           // local col 0..124
    const int rb = t >> 5;                 // row offset 0..7
    const int n = n0 + c4;
    if (n + 3 < PAR) {                     // fast path (all tiles except last n0)
        const float4 ev = *reinterpret_cast<const float4*>(e + n);
        const float a0 = 0.7f * ev.x, a1 = 0.7f * ev.y;
        const float a2 = 0.7f * ev.z, a3 = 0.7f * ev.w;
        #pragma unroll 4
        for (int it = 0; it < 8; ++it) {
            int row = it * 8 + rb;
            int m = m0 + row;
            const float* tpp = tp + (size_t)m * PAR + n;
            float2 tv0 = *reinterpret_cast<const float2*>(tpp);      // 8B-aligned always
            float2 tv1 = *reinterpret_cast<const float2*>(tpp + 2);
            uint2 cw = *reinterpret_cast<const uint2*>(&corr[row][c4]);
            float4 o;
            o.x = fast_tanh(a0 + 0.3f * tv0.x) - bf2f((unsigned short)(cw.x & 0xFFFF));
            o.y = fast_tanh(a1 + 0.3f * tv0.y) - bf2f((unsigned short)(cw.x >> 16));
            o.z = fast_tanh(a2 + 0.3f * tv1.x) - bf2f((unsigned short)(cw.y & 0xFFFF));
            o.w = fast_tanh(a3 + 0.3f * tv1.y) - bf2f((unsigned short)(cw.y >> 16));
            *reinterpret_cast<float4*>(pm + (size_t)m * PDIM + n) = o;
        }
    } else {                               // boundary lanes: per-element
        for (int it = 0; it < 8; ++it) {
            int row = it * 8 + rb;
            int m = m0 + row;
            #pragma unroll
            for (int jj = 0; jj < 4; ++jj) {
                int nn = n + jj;
                float v = (nn < PAR) ? tp[(size_t)m * PAR + nn] : cons[m * CONS + (nn - PAR)];
                pm[(size_t)m * PDIM + nn] = fast_tanh(0.7f * e[nn] + 0.3f * v)
                                          - bf2f(corr[row][c4 + jj]);
            }
        }
    }
}

extern "C" void kernel_launch(void* const* d_in, const int* in_sizes, int n_in,
                              void* d_out, int out_size, void* d_ws, size_t ws_size,
                              hipStream_t stream) {
    const float* tp   = (const float*)d_in[0];
    const float* cons = (const float*)d_in[1];
    // d_in[2] transverse_field, d_in[3] coupling: DEAD CODE (annealing is identity)
    const float* mp   = (const float*)d_in[4];
    const float* cw1  = (const float*)d_in[5];
    const float* cb1  = (const float*)d_in[6];
    const float* cw2  = (const float*)d_in[7];
    const float* cb2  = (const float*)d_in[8];
    const float* ow1  = (const float*)d_in[9];
    const float* ob1  = (const float*)d_in[10];
    const float* ow2  = (const float*)d_in[11];
    const float* ob2  = (const float*)d_in[12];
    const float* ow3  = (const float*)d_in[13];
    float* pm = (float*)d_out;

    float* f = (float*)d_ws;
    float* e      = f;  f += 4096;
    float* epart  = f;  f += 32 * 4096;
    float* Gpart  = f;  f += 8 * NW * NW;
    unsigned short* u = (unsigned short*)f;
    unsigned short* Tparts = u;  u += (size_t)KZT * BATCH * NW;   // bf16 partials
    unsigned short* WT   = u;  u += NW * PDIM;
    unsigned short* Wcat = u;  u += PDIM * NW;
    unsigned short* Gram = u;  u += NW * NW;
    unsigned short* Dsbf = u;  u += BATCH * NW;
    unsigned short* Wpk  = u;

    prep_all_k<<<4068, 256, 0, stream>>>(mp, cw1, ow1, ow2, epart, WT, Wcat, cw2, Wpk);
    fin_gram_k<<<88, 256, 0, stream>>>(epart, WT, e, Gpart);
    gemmT_k<<<656, 256, 0, stream>>>(tp, cons, e, WT, Tparts, Gpart, Gram);
    refine_k<<<256, 256, 0, stream>>>(Tparts, cb1, cb2, ob1, ob2, ow3, Wpk, Gram, Dsbf);
    final_k<<<1024, 256, 0, stream>>>(Dsbf, Wcat, tp, cons, e, pm);
}